// Round 3
// baseline (273.588 us; speedup 1.0000x reference)
//
#include <hip/hip_runtime.h>

// GroupTokenizer: y [B,T,C] f32, edges [C,K] f32 -> labels [B,T,C] (as f32), reg [B,T,C,K] f32.
// B=32 T=4096 C=8 K=64. N = B*T*C = 1048576. Output = 272.6 MB -> streaming-store bound.
#define N_ELEM (32 * 4096 * 8)
#define CCH 8
#define KB 64

typedef float vfloat4 __attribute__((ext_vector_type(4)));  // clang vector: valid for nontemporal builtin

__global__ __launch_bounds__(256) void group_tokenizer_kernel(
    const float* __restrict__ y,
    const float* __restrict__ le,
    const float* __restrict__ re,
    float* __restrict__ out,
    int ngroups) {
  // Edges in LDS, stride K+1=65 so bank = (c + k) % 32 (distinct across the 8 channels;
  // same-channel lanes hit identical addresses -> broadcast, free).
  __shared__ float ls[CCH][KB + 1];
  __shared__ float rs[CCH][KB + 1];
  const int tid = threadIdx.x;
  for (int t = tid; t < CCH * KB; t += blockDim.x) {
    ls[t >> 6][t & 63] = le[t];
    rs[t >> 6][t & 63] = re[t];
  }
  __syncthreads();

  const int lane = tid & 63;
  const int wid = tid >> 6;
  const int wavesPerBlock = blockDim.x >> 6;
  const int gwave = blockIdx.x * wavesPerBlock + wid;
  const int nwaves = gridDim.x * wavesPerBlock;

  for (int g = gwave; g < ngroups; g += nwaves) {
    const int e = g * 64 + lane;           // element index (lane-contiguous)
    const float yv = y[e];
    const int c = e & (CCH - 1);           // e % 8 == lane % 8 (group base divisible by 64)
    const float* lr = ls[c];
    const float* rr = rs[c];

    // lower_bound on r: first k with yv < r[k]. 65 possible answers (0..64) ->
    // SEVEN branchless steps (6 leaves a size-1 interval untested: that was the
    // round-2 off-by-one that produced the absmax=2.0 reg mismatch).
    int lo = 0, hi = KB;
#pragma unroll
    for (int it = 0; it < 7; ++it) {
      const int mid = (lo + hi) >> 1;
      const bool cond = yv < rr[mid];
      hi = cond ? mid : hi;
      lo = cond ? lo : mid + 1;
    }
    // in_bin[lo] iff yv >= l[lo]; otherwise no bin anywhere -> label K-1.
    // (lo==KB read is safe: arrays padded to KB+1.)
    const int label = (lo < KB && yv >= lr[lo]) ? lo : (KB - 1);

    const float left = lr[label];
    const float right = rs[c][label];
    const float width = fmaxf(right - left, 1e-12f);
    float delta = (yv - left) / width;
    delta = fminf(fmaxf(delta, 0.0f), 1.0f);

    // labels output (as float), coalesced 4B/lane.
    out[e] = (float)label;

    // reg output: wave tile = 64 elems * 64 bins = 4096 floats = 16 KB contiguous.
    // 16 iterations of fully-coalesced float4 stores (4 KB/iter/wave).
    vfloat4* regv = (vfloat4*)(out + (size_t)N_ELEM + (size_t)g * (64 * KB));
    const int kst = (lane & 15) << 2;      // this lane's k-offset within its element
#pragma unroll
    for (int j = 0; j < 16; ++j) {
      const int src = (j << 2) + (lane >> 4);   // which lane's element this float4 belongs to
      const int lbl = __shfl(label, src, 64);
      const float dlt = __shfl(delta, src, 64);
      vfloat4 v;
      v.x = (kst + 0 == lbl) ? dlt : -1.0f;
      v.y = (kst + 1 == lbl) ? dlt : -1.0f;
      v.z = (kst + 2 == lbl) ? dlt : -1.0f;
      v.w = (kst + 3 == lbl) ? dlt : -1.0f;
      __builtin_nontemporal_store(v, &regv[(j << 6) + lane]);
    }
  }
}

extern "C" void kernel_launch(void* const* d_in, const int* in_sizes, int n_in,
                              void* d_out, int out_size, void* d_ws, size_t ws_size,
                              hipStream_t stream) {
  const float* y = (const float*)d_in[0];
  const float* le = (const float*)d_in[1];
  const float* re = (const float*)d_in[2];
  float* out = (float*)d_out;

  const int n = in_sizes[0];          // 1048576
  const int ngroups = n / 64;         // 16384 wave-tiles
  const int wavesPerBlock = 4;        // 256 threads
  const int blocks = (ngroups + wavesPerBlock - 1) / wavesPerBlock;  // 4096

  group_tokenizer_kernel<<<blocks, 256, 0, stream>>>(y, le, re, out, ngroups);
}

// Round 4
// 272.002 us; speedup vs baseline: 1.0058x; 1.0058x over previous
//
#include <hip/hip_runtime.h>

// GroupTokenizer: y [B,T,C] f32, edges [C,K] f32 -> labels [B,T,C] (as f32), reg [B,T,C,K] f32.
// B=32 T=4096 C=8 K=64. N = B*T*C = 1048576. Output = 272.6 MB -> streaming-store bound.
// R3->R4: dropped __builtin_nontemporal_store (nt bit suspected of defeating L2
// write path; harness fill kernel sustains 6.4 TB/s on same buffer with plain stores
// while nt version ran at ~1 TB/s).
#define N_ELEM (32 * 4096 * 8)
#define CCH 8
#define KB 64

typedef float vfloat4 __attribute__((ext_vector_type(4)));

__global__ __launch_bounds__(256) void group_tokenizer_kernel(
    const float* __restrict__ y,
    const float* __restrict__ le,
    const float* __restrict__ re,
    float* __restrict__ out,
    int ngroups) {
  // Edges in LDS, stride K+1=65 so bank = (c + k) % 32 (distinct across the 8 channels;
  // same-channel lanes hit identical addresses -> broadcast, free).
  __shared__ float ls[CCH][KB + 1];
  __shared__ float rs[CCH][KB + 1];
  const int tid = threadIdx.x;
  for (int t = tid; t < CCH * KB; t += blockDim.x) {
    ls[t >> 6][t & 63] = le[t];
    rs[t >> 6][t & 63] = re[t];
  }
  __syncthreads();

  const int lane = tid & 63;
  const int wid = tid >> 6;
  const int wavesPerBlock = blockDim.x >> 6;
  const int gwave = blockIdx.x * wavesPerBlock + wid;
  const int nwaves = gridDim.x * wavesPerBlock;

  for (int g = gwave; g < ngroups; g += nwaves) {
    const int e = g * 64 + lane;           // element index (lane-contiguous)
    const float yv = y[e];
    const int c = e & (CCH - 1);           // e % 8 == lane % 8 (group base divisible by 64)
    const float* lr = ls[c];
    const float* rr = rs[c];

    // lower_bound on r: first k with yv < r[k]. 65 possible answers (0..64) ->
    // SEVEN branchless steps (6 left a size-1 interval untested -> round-2 absmax=2.0 bug).
    int lo = 0, hi = KB;
#pragma unroll
    for (int it = 0; it < 7; ++it) {
      const int mid = (lo + hi) >> 1;
      const bool cond = yv < rr[mid];
      hi = cond ? mid : hi;
      lo = cond ? lo : mid + 1;
    }
    // in_bin[lo] iff yv >= l[lo]; otherwise no bin anywhere -> label K-1.
    // (lo==KB read is safe: arrays padded to KB+1.)
    const int label = (lo < KB && yv >= lr[lo]) ? lo : (KB - 1);

    const float left = lr[label];
    const float right = rr[label];
    const float width = fmaxf(right - left, 1e-12f);
    float delta = (yv - left) / width;
    delta = fminf(fmaxf(delta, 0.0f), 1.0f);

    // labels output (as float), coalesced 4B/lane.
    out[e] = (float)label;

    // reg output: wave tile = 64 elems * 64 bins = 4096 floats = 16 KB contiguous.
    // 16 iterations of fully-coalesced float4 stores (1 KB/instr/wave, full lines).
    vfloat4* regv = (vfloat4*)(out + (size_t)N_ELEM + (size_t)g * (64 * KB));
    const int kst = (lane & 15) << 2;      // this lane's k-offset within its element
#pragma unroll
    for (int j = 0; j < 16; ++j) {
      const int src = (j << 2) + (lane >> 4);   // which lane's element this float4 belongs to
      const int lbl = __shfl(label, src, 64);
      const float dlt = __shfl(delta, src, 64);
      vfloat4 v;
      v.x = (kst + 0 == lbl) ? dlt : -1.0f;
      v.y = (kst + 1 == lbl) ? dlt : -1.0f;
      v.z = (kst + 2 == lbl) ? dlt : -1.0f;
      v.w = (kst + 3 == lbl) ? dlt : -1.0f;
      regv[(j << 6) + lane] = v;
    }
  }
}

extern "C" void kernel_launch(void* const* d_in, const int* in_sizes, int n_in,
                              void* d_out, int out_size, void* d_ws, size_t ws_size,
                              hipStream_t stream) {
  const float* y = (const float*)d_in[0];
  const float* le = (const float*)d_in[1];
  const float* re = (const float*)d_in[2];
  float* out = (float*)d_out;

  const int n = in_sizes[0];          // 1048576
  const int ngroups = n / 64;         // 16384 wave-tiles
  const int wavesPerBlock = 4;        // 256 threads
  const int blocks = (ngroups + wavesPerBlock - 1) / wavesPerBlock;  // 4096

  group_tokenizer_kernel<<<blocks, 256, 0, stream>>>(y, le, re, out, ngroups);
}